// Round 11
// baseline (314.381 us; speedup 1.0000x reference)
//
#include <hip/hip_runtime.h>
#include <hip/hip_fp16.h>

typedef unsigned short u16;
typedef unsigned int   u32;
typedef u16   u16x8  __attribute__((ext_vector_type(8)));
typedef u16   u16x4  __attribute__((ext_vector_type(4)));
typedef u16   u16x2  __attribute__((ext_vector_type(2)));
typedef short bf16x8 __attribute__((ext_vector_type(8)));
typedef float f32x4  __attribute__((ext_vector_type(4)));

#define GG 16          // edge chunks per type (20000 edges/chunk; u16-packed LDS counts OK)
#define MAXN2 10016    // >= Nn/2 (Nn=20000), u32 words of packed counters

__device__ inline u16 f2bf_rne(float f) {
    unsigned u = __float_as_uint(f);
    u += 0x7FFFu + ((u >> 16) & 1u);
    return (u16)(u >> 16);
}
__device__ inline float bf2f(u16 h) { return __uint_as_float(((unsigned)h) << 16); }
__device__ inline float h2f(u16 h) { return __half2float(__ushort_as_half(h)); }
__device__ inline u16 f2h(float f) { return __half_as_ushort(__float2half(f)); }

// ---------------- per-block LDS histogram (no global atomics) ----------------
// grid (GG, side, 3); hist[((z*2+side)*GG + b) * Nn + node] (u16)
__global__ __launch_bounds__(256)
void hist_kernel(const int* __restrict__ s0, const int* __restrict__ d0,
                 const int* __restrict__ s1, const int* __restrict__ d1,
                 const int* __restrict__ s2, const int* __restrict__ d2,
                 u16* __restrict__ hist, int E, int Nn)
{
    const int b = blockIdx.x, side = blockIdx.y, z = blockIdx.z;
    const int* arr;
    if (side == 0) arr = (z == 0) ? s0 : ((z == 1) ? s1 : s2);
    else           arr = (z == 0) ? d0 : ((z == 1) ? d1 : d2);

    __shared__ u32 cnt[MAXN2];
    const int tid = threadIdx.x;
    const int half = Nn >> 1;
    for (int i = tid; i < half; i += 256) cnt[i] = 0;
    __syncthreads();

    const int chunk = (E + GG - 1) / GG;
    const int beg = b * chunk;
    const int end = min(E, beg + chunk);
    for (int e = beg + tid; e < end; e += 256) {
        const int nd = arr[e];
        atomicAdd(&cnt[nd >> 1], 1u << ((nd & 1) * 16));
    }
    __syncthreads();

    u32* row = (u32*)(hist + ((size_t)(z * 2 + side) * GG + b) * Nn);
    for (int i = tid; i < half; i += 256) row[i] = cnt[i];
}

// ---------------- sum hist over blocks -> deg + scales ----------------
__global__ __launch_bounds__(256)
void sumdeg_scales_kernel(const u16* __restrict__ hist,
                          int* __restrict__ deg, float* __restrict__ scales, int Nn)
{
    int id = blockIdx.x * 256 + threadIdx.x;
    if (id >= 6 * Nn) return;
    const int zs = id / Nn, node = id - zs * Nn;
    const u16* base = hist + (size_t)zs * GG * Nn + node;
    int sum = 0;
    #pragma unroll
    for (int b = 0; b < GG; ++b) sum += base[(size_t)b * Nn];
    const int side = zs & 1, z = zs >> 1;
    const int di = (side == 0 ? z : 3 + z) * Nn + node;
    deg[di] = sum;
    scales[di] = rsqrtf((float)max(sum, 1));
}

// ---------------- exclusive scan of in-degrees -> CSR rowptr ----------------
__global__ __launch_bounds__(1024)
void scan_rowptr_kernel(const int* __restrict__ deg,
                        int* __restrict__ rowptr,
                        int Nn)
{
    const int z = blockIdx.x;
    const int* d = deg + (size_t)(3 + z) * Nn;
    int* rp = rowptr + (size_t)z * (Nn + 1);
    const int t = threadIdx.x;
    const int chunk = (Nn + 1023) / 1024;
    const int beg = t * chunk;
    const int end = min(beg + chunk, Nn);

    int partial = 0;
    for (int i = beg; i < end; ++i) partial += d[i];

    __shared__ int s[1024];
    s[t] = partial;
    __syncthreads();
    #pragma unroll
    for (int off = 1; off < 1024; off <<= 1) {
        int v = (t >= off) ? s[t - off] : 0;
        __syncthreads();
        s[t] += v;
        __syncthreads();
    }
    const int excl = s[t] - partial;

    int run = excl;
    for (int i = beg; i < end; ++i) { rp[i] = run; run += d[i]; }
    if (t == 1023) rp[Nn] = s[1023];
}

// ---------------- per-(node,block) slot offsets for fill ----------------
__global__ __launch_bounds__(256)
void offsets_kernel(const u16* __restrict__ hist, const int* __restrict__ rowptr,
                    u32* __restrict__ offu, int Nn)
{
    int id = blockIdx.x * 256 + threadIdx.x;
    if (id >= 3 * Nn) return;
    const int z = id / Nn, node = id - z * Nn;
    const u16* hbase = hist + ((size_t)(z * 2 + 1) * GG) * Nn + node;
    u32* obase = offu + (size_t)z * GG * Nn + node;
    u32 run = (u32)rowptr[(size_t)z * (Nn + 1) + node];
    #pragma unroll
    for (int b = 0; b < GG; ++b) {
        const u32 c = hbase[(size_t)b * Nn];
        obase[(size_t)b * Nn] = run;
        run += c;
    }
}

// ---------------- all fp32->bf16 hi/lo conversions in one launch ----------------
// ranges: [0,n1) W0^T (3 types, F1=256 x K1p=320, K=300)
//         [n1,n1+n2) W1^T (3 types, F2=128 x K2p=256)
//         [n1+n2,n1+n2+n3) x padded (Mpad x 320, Nn x 300 real)
__global__ __launch_bounds__(256)
void convert_all_kernel(const float* __restrict__ x,
                        const float* __restrict__ W0a, const float* __restrict__ W0b,
                        const float* __restrict__ W0c,
                        const float* __restrict__ W1a, const float* __restrict__ W1b,
                        const float* __restrict__ W1c,
                        u16* __restrict__ wt1h, u16* __restrict__ wt1l,
                        u16* __restrict__ wt2h, u16* __restrict__ wt2l,
                        u16* __restrict__ xh, u16* __restrict__ xl,
                        int Nn, int n1, int n2, int n3)
{
    int id = blockIdx.x * 256 + threadIdx.x;
    float v;
    u16 *th, *tl;
    int outi;
    if (id < n1) {
        const int per = 256 * 320;
        const int z = id / per, rem = id - z * per;
        const int n = rem / 320, kp = rem - n * 320;
        const float* W = (z == 0) ? W0a : ((z == 1) ? W0b : W0c);
        v = (kp < 300) ? W[kp * 256 + n] : 0.f;
        th = wt1h; tl = wt1l; outi = id;
    } else if (id < n1 + n2) {
        const int id2 = id - n1;
        const int per = 128 * 256;
        const int z = id2 / per, rem = id2 - z * per;
        const int n = rem / 256, kp = rem - n * 256;
        const float* W = (z == 0) ? W1a : ((z == 1) ? W1b : W1c);
        v = W[kp * 128 + n];
        th = wt2h; tl = wt2l; outi = id2;
    } else if (id < n1 + n2 + n3) {
        const int id3 = id - n1 - n2;
        const int r = id3 / 320, kp = id3 - r * 320;
        v = (r < Nn && kp < 300) ? x[(size_t)r * 300 + kp] : 0.f;
        th = xh; tl = xl; outi = id3;
    } else return;
    const u16 hi = f2bf_rne(v);
    th[outi] = hi;
    tl[outi] = f2bf_rne(v - bf2f(hi));
}

// ---------------- fused {CSR-fill | split-bf16 MFMA GEMM} dispatch ----------------
// blocks [0,nFill): CSR fill via LDS rank; blocks [nFill, nFill+NBX*NBY*3): GEMM.
// Shared 40KB LDS region unioned between the two paths.
template<int KSTEPS>
__global__ __launch_bounds__(256)
void gemm_fill_kernel(const u16* __restrict__ Ah, const u16* __restrict__ Al,
                      const u16* __restrict__ B0h, const u16* __restrict__ B0l,
                      const u16* __restrict__ B1h, const u16* __restrict__ B1l,
                      const u16* __restrict__ B2h, const u16* __restrict__ B2l,
                      const float* __restrict__ scales,
                      u16* __restrict__ Cbase, int M, int Ncols,
                      int NBX, int NBY,
                      const int* __restrict__ s0, const int* __restrict__ d0,
                      const int* __restrict__ s1, const int* __restrict__ d1,
                      const int* __restrict__ s2, const int* __restrict__ d2,
                      const u32* __restrict__ offu, int* __restrict__ csr,
                      int E, int nFill)
{
    __shared__ u32 smem[MAXN2];   // 40064 B; GEMM uses first 32768 B
    const int tid = threadIdx.x;

    if ((int)blockIdx.x < nFill) {
        // ---- CSR fill path ----
        const int fb = blockIdx.x;
        const int z = fb / GG, b = fb - z * GG;
        const int* sp = (z == 0) ? s0 : ((z == 1) ? s1 : s2);
        const int* dp = (z == 0) ? d0 : ((z == 1) ? d1 : d2);
        const int half = M >> 1;   // M == Nn
        for (int i = tid; i < half; i += 256) smem[i] = 0;
        __syncthreads();
        const u32* orow = offu + ((size_t)z * GG + b) * M;
        int* crow = csr + (size_t)z * E;
        const int chunk = (E + GG - 1) / GG;
        const int beg = b * chunk;
        const int end = min(E, beg + chunk);
        for (int e = beg + tid; e < end; e += 256) {
            const int d = dp[e];
            const int s = sp[e];
            const u32 old = atomicAdd(&smem[d >> 1], 1u << ((d & 1) * 16));
            const u32 rank = (old >> ((d & 1) * 16)) & 0xFFFFu;
            crow[orow[d] + rank] = s;
        }
        return;
    }

    // ---- GEMM path ----
    const int g2 = blockIdx.x - nFill;
    const int bx = g2 % NBX;
    const int by = (g2 / NBX) % NBY;
    const int z = g2 / (NBX * NBY);

    u16* Ash = (u16*)smem;            // +0      (8192 B)
    u16* Asl = (u16*)smem + 4096;     // +8192
    u16* Bsh = (u16*)smem + 8192;     // +16384
    u16* Bsl = (u16*)smem + 12288;    // +24576

    const u16* Bh = (z == 0) ? B0h : ((z == 1) ? B1h : B2h);
    const u16* Bl = (z == 0) ? B0l : ((z == 1) ? B1l : B2l);
    const float* s = scales + (size_t)z * M;
    u16* C = Cbase + (size_t)z * M * Ncols;
    const int Kpad = KSTEPS * 32;

    const int lane = tid & 63;
    const int wv   = tid >> 6;
    const int wr   = wv >> 1, wc = wv & 1;
    const int g    = lane >> 4, lm = lane & 15;
    const int row0 = by * 128, col0 = bx * 128;

    const int sr = tid >> 1;
    const int sh = tid & 1;
    const int swz = (sr >> 1) & 3;
    const int c0 = ((sh * 2 + 0) ^ swz) << 4;
    const int c1 = ((sh * 2 + 1) ^ swz) << 4;
    const size_t abase = (size_t)(row0 + sr) * Kpad;
    const size_t bbase = (size_t)(col0 + sr) * Kpad;

    f32x4 acc[4][4];
    #pragma unroll
    for (int i = 0; i < 4; ++i)
        #pragma unroll
        for (int j = 0; j < 4; ++j) acc[i][j] = 0.f;

    // prologue: prefetch tile 0 into registers
    const int kg = sh * 16;
    u16x8 ah0 = *(const u16x8*)(Ah + abase + kg);
    u16x8 ah1 = *(const u16x8*)(Ah + abase + kg + 8);
    u16x8 al0 = *(const u16x8*)(Al + abase + kg);
    u16x8 al1 = *(const u16x8*)(Al + abase + kg + 8);
    u16x8 bh0 = *(const u16x8*)(Bh + bbase + kg);
    u16x8 bh1 = *(const u16x8*)(Bh + bbase + kg + 8);
    u16x8 bl0 = *(const u16x8*)(Bl + bbase + kg);
    u16x8 bl1 = *(const u16x8*)(Bl + bbase + kg + 8);

    for (int st = 0; st < KSTEPS; ++st) {
        {
            char* pAh = (char*)Ash + sr * 64;
            char* pAl = (char*)Asl + sr * 64;
            char* pBh = (char*)Bsh + sr * 64;
            char* pBl = (char*)Bsl + sr * 64;
            *(u16x8*)(pAh + c0) = ah0;
            *(u16x8*)(pAh + c1) = ah1;
            *(u16x8*)(pAl + c0) = al0;
            *(u16x8*)(pAl + c1) = al1;
            *(u16x8*)(pBh + c0) = bh0;
            *(u16x8*)(pBh + c1) = bh1;
            *(u16x8*)(pBl + c0) = bl0;
            *(u16x8*)(pBl + c1) = bl1;
        }
        __syncthreads();

        if (st + 1 < KSTEPS) {
            const int kgn = (st + 1) * 32 + sh * 16;
            ah0 = *(const u16x8*)(Ah + abase + kgn);
            ah1 = *(const u16x8*)(Ah + abase + kgn + 8);
            al0 = *(const u16x8*)(Al + abase + kgn);
            al1 = *(const u16x8*)(Al + abase + kgn + 8);
            bh0 = *(const u16x8*)(Bh + bbase + kgn);
            bh1 = *(const u16x8*)(Bh + bbase + kgn + 8);
            bl0 = *(const u16x8*)(Bl + bbase + kgn);
            bl1 = *(const u16x8*)(Bl + bbase + kgn + 8);
        }

        bf16x8 afh[4], afl[4], bfh[4], bfl[4];
        #pragma unroll
        for (int mi = 0; mi < 4; ++mi) {
            const int r = wr * 64 + mi * 16 + lm;
            const int byte = r * 64 + ((g ^ ((r >> 1) & 3)) << 4);
            afh[mi] = *(const bf16x8*)((const char*)Ash + byte);
            afl[mi] = *(const bf16x8*)((const char*)Asl + byte);
        }
        #pragma unroll
        for (int ni = 0; ni < 4; ++ni) {
            const int r = wc * 64 + ni * 16 + lm;
            const int byte = r * 64 + ((g ^ ((r >> 1) & 3)) << 4);
            bfh[ni] = *(const bf16x8*)((const char*)Bsh + byte);
            bfl[ni] = *(const bf16x8*)((const char*)Bsl + byte);
        }
        #pragma unroll
        for (int mi = 0; mi < 4; ++mi)
            #pragma unroll
            for (int ni = 0; ni < 4; ++ni) {
                acc[mi][ni] = __builtin_amdgcn_mfma_f32_16x16x32_bf16(afl[mi], bfh[ni], acc[mi][ni], 0, 0, 0);
                acc[mi][ni] = __builtin_amdgcn_mfma_f32_16x16x32_bf16(afh[mi], bfl[ni], acc[mi][ni], 0, 0, 0);
                acc[mi][ni] = __builtin_amdgcn_mfma_f32_16x16x32_bf16(afh[mi], bfh[ni], acc[mi][ni], 0, 0, 0);
            }

        __syncthreads();
    }

    #pragma unroll
    for (int mi = 0; mi < 4; ++mi) {
        #pragma unroll
        for (int reg = 0; reg < 4; ++reg) {
            const int r = row0 + wr * 64 + mi * 16 + g * 4 + reg;
            if (r < M) {
                const float sc = s[r];
                #pragma unroll
                for (int ni = 0; ni < 4; ++ni) {
                    C[(size_t)r * Ncols + col0 + wc * 64 + ni * 16 + lm] = f2h(acc[mi][ni][reg] * sc);
                }
            }
        }
    }
}

// ---------------- fused CSR-gather (fp16 payload) + dual-attention ----------------
template <int F, int VEC, bool LEAKY01, bool FUSE_FC, bool OUT_SPLIT>
__global__ __launch_bounds__(256)
void gather_attn_kernel(const u16* __restrict__ pre,
                        const int* __restrict__ rowptr,
                        const int* __restrict__ csr,
                        const float* __restrict__ sin_,
                        const float* __restrict__ bb0, const float* __restrict__ bb1,
                        const float* __restrict__ bb2,
                        const float* __restrict__ a,
                        const float* __restrict__ fcw,
                        const float* __restrict__ fcb,
                        float* __restrict__ out,
                        u16* __restrict__ outh, u16* __restrict__ outl,
                        float* __restrict__ logits,
                        int Nn, int E)
{
    const int wave = blockIdx.x * 4 + (threadIdx.x >> 6);
    const int lane = threadIdx.x & 63;
    if (wave >= Nn) return;
    const int n = wave;
    const size_t NF = (size_t)Nn * F;
    const int fo = lane * VEC;

    float ht[3][VEC];
    float mean[VEC];
    #pragma unroll
    for (int v = 0; v < VEC; ++v) mean[v] = 0.f;

    const float* bptr[3] = {bb0, bb1, bb2};
    #pragma unroll
    for (int t = 0; t < 3; ++t) {
        const int* rp = rowptr + (size_t)t * (Nn + 1);
        const int beg = rp[n];
        const int end = rp[n + 1];
        const int* lst = csr + (size_t)t * E;
        const u16* P = pre + t * NF;

        float a0v[VEC], a1v[VEC], a2v[VEC], a3v[VEC];
        #pragma unroll
        for (int v = 0; v < VEC; ++v) { a0v[v] = 0.f; a1v[v] = 0.f; a2v[v] = 0.f; a3v[v] = 0.f; }

        for (int j = beg; j < end; j += 64) {
            const int cnt = min(64, end - j);
            int myIdx = (lane < cnt) ? lst[j + lane] : 0;
            int k = 0;
            for (; k + 4 <= cnt; k += 4) {
                const int s0 = __shfl(myIdx, k + 0);
                const int s1 = __shfl(myIdx, k + 1);
                const int s2 = __shfl(myIdx, k + 2);
                const int s3 = __shfl(myIdx, k + 3);
                if constexpr (VEC == 4) {
                    u16x4 r0 = *reinterpret_cast<const u16x4*>(P + (size_t)s0 * F + fo);
                    u16x4 r1 = *reinterpret_cast<const u16x4*>(P + (size_t)s1 * F + fo);
                    u16x4 r2 = *reinterpret_cast<const u16x4*>(P + (size_t)s2 * F + fo);
                    u16x4 r3 = *reinterpret_cast<const u16x4*>(P + (size_t)s3 * F + fo);
                    #pragma unroll
                    for (int v = 0; v < 4; ++v) a0v[v] += h2f(r0[v]);
                    #pragma unroll
                    for (int v = 0; v < 4; ++v) a1v[v] += h2f(r1[v]);
                    #pragma unroll
                    for (int v = 0; v < 4; ++v) a2v[v] += h2f(r2[v]);
                    #pragma unroll
                    for (int v = 0; v < 4; ++v) a3v[v] += h2f(r3[v]);
                } else {
                    u16x2 r0 = *reinterpret_cast<const u16x2*>(P + (size_t)s0 * F + fo);
                    u16x2 r1 = *reinterpret_cast<const u16x2*>(P + (size_t)s1 * F + fo);
                    u16x2 r2 = *reinterpret_cast<const u16x2*>(P + (size_t)s2 * F + fo);
                    u16x2 r3 = *reinterpret_cast<const u16x2*>(P + (size_t)s3 * F + fo);
                    a0v[0] += h2f(r0[0]); a0v[1] += h2f(r0[1]);
                    a1v[0] += h2f(r1[0]); a1v[1] += h2f(r1[1]);
                    a2v[0] += h2f(r2[0]); a2v[1] += h2f(r2[1]);
                    a3v[0] += h2f(r3[0]); a3v[1] += h2f(r3[1]);
                }
            }
            for (; k < cnt; ++k) {
                const int sI = __shfl(myIdx, k);
                const u16* rowp = P + (size_t)sI * F + fo;
                if constexpr (VEC == 4) {
                    u16x4 r4 = *reinterpret_cast<const u16x4*>(rowp);
                    #pragma unroll
                    for (int v = 0; v < 4; ++v) a0v[v] += h2f(r4[v]);
                } else {
                    u16x2 r2 = *reinterpret_cast<const u16x2*>(rowp);
                    a0v[0] += h2f(r2[0]); a0v[1] += h2f(r2[1]);
                }
            }
        }

        const float si = sin_[t * Nn + n];
        const float* bp = bptr[t] + fo;
        #pragma unroll
        for (int v = 0; v < VEC; ++v) {
            const float sum = (a0v[v] + a1v[v]) + (a2v[v] + a3v[v]);
            const float xv = fmaf(sum, si, bp[v]);
            ht[t][v] = xv;
            mean[v] += xv;
        }
    }
    #pragma unroll
    for (int v = 0; v < VEC; ++v) mean[v] *= (1.0f / 3.0f);

    float p0 = 0.f, p1 = 0.f, p2 = 0.f, p3 = 0.f;
    #pragma unroll
    for (int v = 0; v < VEC; ++v) {
        const float aA = a[fo + v];
        const float aB = a[F + fo + v];
        p0 = fmaf(ht[0][v], aA, p0);
        p1 = fmaf(ht[1][v], aA, p1);
        p2 = fmaf(ht[2][v], aA, p2);
        p3 = fmaf(mean[v], aB, p3);
    }
    #pragma unroll
    for (int off = 1; off < 64; off <<= 1) {
        p0 += __shfl_xor(p0, off);
        p1 += __shfl_xor(p1, off);
        p2 += __shfl_xor(p2, off);
        p3 += __shfl_xor(p3, off);
    }
    float sc0 = p0 + p3, sc1 = p1 + p3, sc2 = p2 + p3;
    sc0 = sc0 > 0.f ? sc0 : 0.2f * sc0;
    sc1 = sc1 > 0.f ? sc1 : 0.2f * sc1;
    sc2 = sc2 > 0.f ? sc2 : 0.2f * sc2;
    const float m = fmaxf(sc0, fmaxf(sc1, sc2));
    const float e0 = __expf(sc0 - m);
    const float e1 = __expf(sc1 - m);
    const float e2 = __expf(sc2 - m);
    const float inv = 1.0f / (e0 + e1 + e2);
    const float at0 = e0 * inv, at1 = e1 * inv, at2 = e2 * inv;

    float o[VEC];
    #pragma unroll
    for (int v = 0; v < VEC; ++v) {
        float ov = at0 * ht[0][v] + at1 * ht[1][v] + at2 * ht[2][v];
        if constexpr (LEAKY01) ov = ov > 0.f ? ov : 0.01f * ov;
        o[v] = ov;
    }

    if constexpr (OUT_SPLIT) {
        u16 oh[VEC], ol[VEC];
        #pragma unroll
        for (int v = 0; v < VEC; ++v) {
            u16 hi = f2bf_rne(o[v]);
            oh[v] = hi;
            ol[v] = f2bf_rne(o[v] - bf2f(hi));
        }
        if constexpr (VEC == 4) {
            *(u16x4*)(outh + (size_t)n * F + fo) = *(u16x4*)oh;
            *(u16x4*)(outl + (size_t)n * F + fo) = *(u16x4*)ol;
        } else {
            *(u16x2*)(outh + (size_t)n * F + fo) = *(u16x2*)oh;
            *(u16x2*)(outl + (size_t)n * F + fo) = *(u16x2*)ol;
        }
    } else {
        float* op = out + (size_t)n * F + fo;
        #pragma unroll
        for (int v = 0; v < VEC; ++v) op[v] = o[v];
    }

    if constexpr (FUSE_FC) {
        float accc[10];
        #pragma unroll
        for (int c = 0; c < 10; ++c) {
            float s = 0.f;
            #pragma unroll
            for (int v = 0; v < VEC; ++v)
                s = fmaf(o[v], fcw[(fo + v) * 10 + c], s);
            accc[c] = s;
        }
        #pragma unroll
        for (int off = 1; off < 64; off <<= 1) {
            #pragma unroll
            for (int c = 0; c < 10; ++c) accc[c] += __shfl_xor(accc[c], off);
        }
        if (lane == 0) {
            #pragma unroll
            for (int c = 0; c < 10; ++c)
                logits[(size_t)n * 10 + c] = accc[c] + fcb[c];
        }
    }
}

extern "C" void kernel_launch(void* const* d_in, const int* in_sizes, int n_in,
                              void* d_out, int out_size, void* d_ws, size_t ws_size,
                              hipStream_t stream)
{
    const float* x = (const float*)d_in[0];
    const int* src[3] = {(const int*)d_in[1], (const int*)d_in[3], (const int*)d_in[5]};
    const int* dst[3] = {(const int*)d_in[2], (const int*)d_in[4], (const int*)d_in[6]};
    const float* W0[3] = {(const float*)d_in[7],  (const float*)d_in[11], (const float*)d_in[15]};
    const float* b0[3] = {(const float*)d_in[8],  (const float*)d_in[12], (const float*)d_in[16]};
    const float* W1[3] = {(const float*)d_in[9],  (const float*)d_in[13], (const float*)d_in[17]};
    const float* b1[3] = {(const float*)d_in[10], (const float*)d_in[14], (const float*)d_in[18]};
    const float* a0  = (const float*)d_in[19];
    const float* a1  = (const float*)d_in[20];
    const float* fcw = (const float*)d_in[21];
    const float* fcb = (const float*)d_in[22];

    const int Nn = in_sizes[0] / 300;  // 20000
    const int E  = in_sizes[1];        // 320000
    const int K1p = 320, F1 = 256;
    const int K2p = 256, F2 = 128;
    const int Mpad = ((Nn + 127) / 128) * 128;  // 20096

    // ---- workspace layout (no aliasing; totals ~90 MB) ----
    char* wsb = (char*)d_ws;
    size_t off = 0;
    auto take = [&](size_t bytes) { char* p = wsb + off; off = (off + bytes + 15) & ~(size_t)15; return p; };
    int*   deg    = (int*)take(6 * (size_t)Nn * sizeof(int));
    float* scales = (float*)take(6 * (size_t)Nn * sizeof(float));
    int*   rowptr = (int*)take(3 * ((size_t)Nn + 1) * sizeof(int));
    int*   csr    = (int*)take(3 * (size_t)E * sizeof(int));
    u16*   hist   = (u16*)take(6 * (size_t)GG * Nn * sizeof(u16));   // 3.84 MB
    u32*   offu   = (u32*)take(3 * (size_t)GG * Nn * sizeof(u32));   // 3.84 MB
    u16*   wt1h   = (u16*)take(3 * (size_t)F1 * K1p * sizeof(u16));
    u16*   wt1l   = (u16*)take(3 * (size_t)F1 * K1p * sizeof(u16));
    u16*   wt2h   = (u16*)take(3 * (size_t)F2 * K2p * sizeof(u16));
    u16*   wt2l   = (u16*)take(3 * (size_t)F2 * K2p * sizeof(u16));
    u16*   buf1   = (u16*)take(3 * (size_t)Nn * 256 * sizeof(u16));
    u16*   xh     = (u16*)take((size_t)Mpad * K1p * sizeof(u16));
    u16*   xl     = (u16*)take((size_t)Mpad * K1p * sizeof(u16));
    u16*   h1h    = (u16*)take((size_t)Mpad * K2p * sizeof(u16));
    u16*   h1l    = (u16*)take((size_t)Mpad * K2p * sizeof(u16));

    float* outH   = (float*)d_out;
    float* logits = outH + (size_t)Nn * 128;

    // K1: histograms (src+dst, 3 types)
    {
        dim3 g(GG, 2, 3);
        hist_kernel<<<g, 256, 0, stream>>>(src[0], dst[0], src[1], dst[1],
                                           src[2], dst[2], hist, E, Nn);
    }
    // K2: all fp32->bf16 hi/lo conversions
    {
        const int n1 = 3 * F1 * K1p;
        const int n2 = 3 * F2 * K2p;
        const int n3 = Mpad * K1p;
        const int total = n1 + n2 + n3;
        convert_all_kernel<<<(total + 255) / 256, 256, 0, stream>>>(
            x, W0[0], W0[1], W0[2], W1[0], W1[1], W1[2],
            wt1h, wt1l, wt2h, wt2l, xh, xl, Nn, n1, n2, n3);
    }
    // K3-K5: degree sums, rowptr scan, fill offsets
    sumdeg_scales_kernel<<<(6 * Nn + 255) / 256, 256, 0, stream>>>(hist, deg, scales, Nn);
    scan_rowptr_kernel<<<3, 1024, 0, stream>>>(deg, rowptr, Nn);
    offsets_kernel<<<(3 * Nn + 255) / 256, 256, 0, stream>>>(hist, rowptr, offu, Nn);

    // K6: layer-1 GEMM with CSR fill fused in (fill = first 48 blocks)
    {
        const int NBX = F1 / 128, NBY = Mpad / 128;  // 2 x 157
        const int nFill = 3 * GG;                    // 48
        const int total = nFill + NBX * NBY * 3;
        gemm_fill_kernel<10><<<total, 256, 0, stream>>>(
            xh, xl,
            wt1h + 0 * (size_t)F1 * K1p, wt1l + 0 * (size_t)F1 * K1p,
            wt1h + 1 * (size_t)F1 * K1p, wt1l + 1 * (size_t)F1 * K1p,
            wt1h + 2 * (size_t)F1 * K1p, wt1l + 2 * (size_t)F1 * K1p,
            scales, buf1, Nn, F1, NBX, NBY,
            src[0], dst[0], src[1], dst[1], src[2], dst[2],
            offu, csr, E, nFill);
    }
    // K7: layer-1 gather+attention (writes h1 pre-split)
    gather_attn_kernel<256, 4, true, false, true><<<(Nn + 3) / 4, 256, 0, stream>>>(
        buf1, rowptr, csr, scales + 3 * (size_t)Nn,
        b0[0], b0[1], b0[2], a0, nullptr, nullptr,
        nullptr, h1h, h1l, nullptr, Nn, E);

    // K8: layer-2 GEMM (no fill)
    {
        const int NBX = F2 / 128, NBY = Mpad / 128;  // 1 x 157
        const int total = NBX * NBY * 3;
        gemm_fill_kernel<8><<<total, 256, 0, stream>>>(
            h1h, h1l,
            wt2h + 0 * (size_t)F2 * K2p, wt2l + 0 * (size_t)F2 * K2p,
            wt2h + 1 * (size_t)F2 * K2p, wt2l + 1 * (size_t)F2 * K2p,
            wt2h + 2 * (size_t)F2 * K2p, wt2l + 2 * (size_t)F2 * K2p,
            scales, buf1, Nn, F2, NBX, NBY,
            src[0], dst[0], src[1], dst[1], src[2], dst[2],
            offu, csr, E, 0);
    }
    // K9: layer-2 gather+attention + FC head
    gather_attn_kernel<128, 2, false, true, false><<<(Nn + 3) / 4, 256, 0, stream>>>(
        buf1, rowptr, csr, scales + 3 * (size_t)Nn,
        b1[0], b1[1], b1[2], a1, fcw, fcb,
        outH, nullptr, nullptr, logits, Nn, E);
}

// Round 12
// 303.030 us; speedup vs baseline: 1.0375x; 1.0375x over previous
//
#include <hip/hip_runtime.h>
#include <hip/hip_fp16.h>

typedef unsigned short u16;
typedef unsigned int   u32;
typedef u16   u16x8  __attribute__((ext_vector_type(8)));
typedef u16   u16x4  __attribute__((ext_vector_type(4)));
typedef u16   u16x2  __attribute__((ext_vector_type(2)));
typedef short bf16x8 __attribute__((ext_vector_type(8)));
typedef float f32x4  __attribute__((ext_vector_type(4)));

#define GG 64          // edge chunks per type (5000 edges/block: short fill blocks)
#define MAXN2 10016    // >= Nn/2 (Nn=20000)

__device__ inline u16 f2bf_rne(float f) {
    unsigned u = __float_as_uint(f);
    u += 0x7FFFu + ((u >> 16) & 1u);
    return (u16)(u >> 16);
}
__device__ inline float bf2f(u16 h) { return __uint_as_float(((unsigned)h) << 16); }
__device__ inline float h2f(u16 h) { return __half2float(__ushort_as_half(h)); }
__device__ inline u16 f2h(float f) { return __half_as_ushort(__float2half(f)); }

// ---------------- per-block LDS histogram (no global atomics) ----------------
__global__ __launch_bounds__(256)
void hist_kernel(const int* __restrict__ s0, const int* __restrict__ d0,
                 const int* __restrict__ s1, const int* __restrict__ d1,
                 const int* __restrict__ s2, const int* __restrict__ d2,
                 u16* __restrict__ hist, int E, int Nn)
{
    const int b = blockIdx.x, side = blockIdx.y, z = blockIdx.z;
    const int* arr;
    if (side == 0) arr = (z == 0) ? s0 : ((z == 1) ? s1 : s2);
    else           arr = (z == 0) ? d0 : ((z == 1) ? d1 : d2);

    __shared__ u32 cnt[MAXN2];
    const int tid = threadIdx.x;
    const int half = Nn >> 1;
    for (int i = tid; i < half; i += 256) cnt[i] = 0;
    __syncthreads();

    const int chunk = (E + GG - 1) / GG;
    const int beg = b * chunk;
    const int end = min(E, beg + chunk);
    for (int e = beg + tid; e < end; e += 256) {
        const int nd = arr[e];
        atomicAdd(&cnt[nd >> 1], 1u << ((nd & 1) * 16));
    }
    __syncthreads();

    u32* row = (u32*)(hist + ((size_t)(z * 2 + side) * GG + b) * Nn);
    for (int i = tid; i < half; i += 256) row[i] = cnt[i];
}

// ---------------- sum hist over blocks -> deg + scales ----------------
__global__ __launch_bounds__(256)
void sumdeg_scales_kernel(const u16* __restrict__ hist,
                          int* __restrict__ deg, float* __restrict__ scales, int Nn)
{
    int id = blockIdx.x * 256 + threadIdx.x;
    if (id >= 6 * Nn) return;
    const int zs = id / Nn, node = id - zs * Nn;
    const u16* base = hist + (size_t)zs * GG * Nn + node;
    int sum = 0;
    #pragma unroll 8
    for (int b = 0; b < GG; ++b) sum += base[(size_t)b * Nn];
    const int side = zs & 1, z = zs >> 1;
    const int di = (side == 0 ? z : 3 + z) * Nn + node;
    deg[di] = sum;
    scales[di] = rsqrtf((float)max(sum, 1));
}

// ---------------- exclusive scan of in-degrees -> CSR rowptr ----------------
__global__ __launch_bounds__(1024)
void scan_rowptr_kernel(const int* __restrict__ deg,
                        int* __restrict__ rowptr,
                        int Nn)
{
    const int z = blockIdx.x;
    const int* d = deg + (size_t)(3 + z) * Nn;
    int* rp = rowptr + (size_t)z * (Nn + 1);
    const int t = threadIdx.x;
    const int chunk = (Nn + 1023) / 1024;
    const int beg = t * chunk;
    const int end = min(beg + chunk, Nn);

    int partial = 0;
    for (int i = beg; i < end; ++i) partial += d[i];

    __shared__ int s[1024];
    s[t] = partial;
    __syncthreads();
    #pragma unroll
    for (int off = 1; off < 1024; off <<= 1) {
        int v = (t >= off) ? s[t - off] : 0;
        __syncthreads();
        s[t] += v;
        __syncthreads();
    }
    const int excl = s[t] - partial;

    int run = excl;
    for (int i = beg; i < end; ++i) { rp[i] = run; run += d[i]; }
    if (t == 1023) rp[Nn] = s[1023];
}

// ---------------- per-(node,block) slot offsets for fill ----------------
__global__ __launch_bounds__(256)
void offsets_kernel(const u16* __restrict__ hist, const int* __restrict__ rowptr,
                    u32* __restrict__ offu, int Nn)
{
    int id = blockIdx.x * 256 + threadIdx.x;
    if (id >= 3 * Nn) return;
    const int z = id / Nn, node = id - z * Nn;
    const u16* hbase = hist + ((size_t)(z * 2 + 1) * GG) * Nn + node;
    u32* obase = offu + (size_t)z * GG * Nn + node;
    u32 run = (u32)rowptr[(size_t)z * (Nn + 1) + node];
    for (int b = 0; b < GG; ++b) {
        const u32 c = hbase[(size_t)b * Nn];
        obase[(size_t)b * Nn] = run;
        run += c;
    }
}

// ---------------- CSR fill via LDS rank (no global atomics) ----------------
__global__ __launch_bounds__(256)
void fill_csr_kernel(const int* __restrict__ s0, const int* __restrict__ d0,
                     const int* __restrict__ s1, const int* __restrict__ d1,
                     const int* __restrict__ s2, const int* __restrict__ d2,
                     const u32* __restrict__ offu,
                     int* __restrict__ csr, int E, int Nn)
{
    const int b = blockIdx.x, z = blockIdx.z;
    const int* sp = (z == 0) ? s0 : ((z == 1) ? s1 : s2);
    const int* dp = (z == 0) ? d0 : ((z == 1) ? d1 : d2);

    __shared__ u32 cur[MAXN2];
    const int tid = threadIdx.x;
    const int half = Nn >> 1;
    for (int i = tid; i < half; i += 256) cur[i] = 0;
    __syncthreads();

    const u32* orow = offu + ((size_t)z * GG + b) * Nn;
    int* crow = csr + (size_t)z * E;
    const int chunk = (E + GG - 1) / GG;
    const int beg = b * chunk;
    const int end = min(E, beg + chunk);
    for (int e = beg + tid; e < end; e += 256) {
        const int d = dp[e];
        const int s = sp[e];
        const u32 old = atomicAdd(&cur[d >> 1], 1u << ((d & 1) * 16));
        const u32 rank = (old >> ((d & 1) * 16)) & 0xFFFFu;
        crow[orow[d] + rank] = s;
    }
}

// ---------------- all fp32->bf16 hi/lo conversions in one launch ----------------
__global__ __launch_bounds__(256)
void convert_all_kernel(const float* __restrict__ x,
                        const float* __restrict__ W0a, const float* __restrict__ W0b,
                        const float* __restrict__ W0c,
                        const float* __restrict__ W1a, const float* __restrict__ W1b,
                        const float* __restrict__ W1c,
                        u16* __restrict__ wt1h, u16* __restrict__ wt1l,
                        u16* __restrict__ wt2h, u16* __restrict__ wt2l,
                        u16* __restrict__ xh, u16* __restrict__ xl,
                        int Nn, int n1, int n2, int n3)
{
    int id = blockIdx.x * 256 + threadIdx.x;
    float v;
    u16 *th, *tl;
    int outi;
    if (id < n1) {
        const int per = 256 * 320;
        const int z = id / per, rem = id - z * per;
        const int n = rem / 320, kp = rem - n * 320;
        const float* W = (z == 0) ? W0a : ((z == 1) ? W0b : W0c);
        v = (kp < 300) ? W[kp * 256 + n] : 0.f;
        th = wt1h; tl = wt1l; outi = id;
    } else if (id < n1 + n2) {
        const int id2 = id - n1;
        const int per = 128 * 256;
        const int z = id2 / per, rem = id2 - z * per;
        const int n = rem / 256, kp = rem - n * 256;
        const float* W = (z == 0) ? W1a : ((z == 1) ? W1b : W1c);
        v = W[kp * 128 + n];
        th = wt2h; tl = wt2l; outi = id2;
    } else if (id < n1 + n2 + n3) {
        const int id3 = id - n1 - n2;
        const int r = id3 / 320, kp = id3 - r * 320;
        v = (r < Nn && kp < 300) ? x[(size_t)r * 300 + kp] : 0.f;
        th = xh; tl = xl; outi = id3;
    } else return;
    const u16 hi = f2bf_rne(v);
    th[outi] = hi;
    tl[outi] = f2bf_rne(v - bf2f(hi));
}

// ---------------- split-bf16 MFMA GEMM with register-prefetch pipeline ----------------
template<int KSTEPS>
__global__ __launch_bounds__(256)
void mfma_gemm_kernel(const u16* __restrict__ Ah, const u16* __restrict__ Al,
                      const u16* __restrict__ B0h, const u16* __restrict__ B0l,
                      const u16* __restrict__ B1h, const u16* __restrict__ B1l,
                      const u16* __restrict__ B2h, const u16* __restrict__ B2l,
                      const float* __restrict__ scales,
                      u16* __restrict__ Cbase, int M, int Ncols)
{
    const int z = blockIdx.z;
    const u16* Bh = (z == 0) ? B0h : ((z == 1) ? B1h : B2h);
    const u16* Bl = (z == 0) ? B0l : ((z == 1) ? B1l : B2l);
    const float* s = scales + (size_t)z * M;
    u16* C = Cbase + (size_t)z * M * Ncols;
    const int Kpad = KSTEPS * 32;

    __shared__ u16 Ash[128 * 32], Asl[128 * 32], Bsh[128 * 32], Bsl[128 * 32];

    const int tid  = threadIdx.x;
    const int lane = tid & 63;
    const int wv   = tid >> 6;
    const int wr   = wv >> 1, wc = wv & 1;
    const int g    = lane >> 4, lm = lane & 15;
    const int row0 = blockIdx.y * 128, col0 = blockIdx.x * 128;

    const int sr = tid >> 1;
    const int sh = tid & 1;
    const int swz = (sr >> 1) & 3;
    const int c0 = ((sh * 2 + 0) ^ swz) << 4;
    const int c1 = ((sh * 2 + 1) ^ swz) << 4;
    const size_t abase = (size_t)(row0 + sr) * Kpad;
    const size_t bbase = (size_t)(col0 + sr) * Kpad;

    f32x4 acc[4][4];
    #pragma unroll
    for (int i = 0; i < 4; ++i)
        #pragma unroll
        for (int j = 0; j < 4; ++j) acc[i][j] = 0.f;

    // prologue: prefetch tile 0 into registers
    const int kg = sh * 16;
    u16x8 ah0 = *(const u16x8*)(Ah + abase + kg);
    u16x8 ah1 = *(const u16x8*)(Ah + abase + kg + 8);
    u16x8 al0 = *(const u16x8*)(Al + abase + kg);
    u16x8 al1 = *(const u16x8*)(Al + abase + kg + 8);
    u16x8 bh0 = *(const u16x8*)(Bh + bbase + kg);
    u16x8 bh1 = *(const u16x8*)(Bh + bbase + kg + 8);
    u16x8 bl0 = *(const u16x8*)(Bl + bbase + kg);
    u16x8 bl1 = *(const u16x8*)(Bl + bbase + kg + 8);

    for (int st = 0; st < KSTEPS; ++st) {
        {
            char* pAh = (char*)Ash + sr * 64;
            char* pAl = (char*)Asl + sr * 64;
            char* pBh = (char*)Bsh + sr * 64;
            char* pBl = (char*)Bsl + sr * 64;
            *(u16x8*)(pAh + c0) = ah0;
            *(u16x8*)(pAh + c1) = ah1;
            *(u16x8*)(pAl + c0) = al0;
            *(u16x8*)(pAl + c1) = al1;
            *(u16x8*)(pBh + c0) = bh0;
            *(u16x8*)(pBh + c1) = bh1;
            *(u16x8*)(pBl + c0) = bl0;
            *(u16x8*)(pBl + c1) = bl1;
        }
        __syncthreads();

        if (st + 1 < KSTEPS) {
            const int kgn = (st + 1) * 32 + sh * 16;
            ah0 = *(const u16x8*)(Ah + abase + kgn);
            ah1 = *(const u16x8*)(Ah + abase + kgn + 8);
            al0 = *(const u16x8*)(Al + abase + kgn);
            al1 = *(const u16x8*)(Al + abase + kgn + 8);
            bh0 = *(const u16x8*)(Bh + bbase + kgn);
            bh1 = *(const u16x8*)(Bh + bbase + kgn + 8);
            bl0 = *(const u16x8*)(Bl + bbase + kgn);
            bl1 = *(const u16x8*)(Bl + bbase + kgn + 8);
        }

        bf16x8 afh[4], afl[4], bfh[4], bfl[4];
        #pragma unroll
        for (int mi = 0; mi < 4; ++mi) {
            const int r = wr * 64 + mi * 16 + lm;
            const int byte = r * 64 + ((g ^ ((r >> 1) & 3)) << 4);
            afh[mi] = *(const bf16x8*)((const char*)Ash + byte);
            afl[mi] = *(const bf16x8*)((const char*)Asl + byte);
        }
        #pragma unroll
        for (int ni = 0; ni < 4; ++ni) {
            const int r = wc * 64 + ni * 16 + lm;
            const int byte = r * 64 + ((g ^ ((r >> 1) & 3)) << 4);
            bfh[ni] = *(const bf16x8*)((const char*)Bsh + byte);
            bfl[ni] = *(const bf16x8*)((const char*)Bsl + byte);
        }
        #pragma unroll
        for (int mi = 0; mi < 4; ++mi)
            #pragma unroll
            for (int ni = 0; ni < 4; ++ni) {
                acc[mi][ni] = __builtin_amdgcn_mfma_f32_16x16x32_bf16(afl[mi], bfh[ni], acc[mi][ni], 0, 0, 0);
                acc[mi][ni] = __builtin_amdgcn_mfma_f32_16x16x32_bf16(afh[mi], bfl[ni], acc[mi][ni], 0, 0, 0);
                acc[mi][ni] = __builtin_amdgcn_mfma_f32_16x16x32_bf16(afh[mi], bfh[ni], acc[mi][ni], 0, 0, 0);
            }

        __syncthreads();
    }

    #pragma unroll
    for (int mi = 0; mi < 4; ++mi) {
        #pragma unroll
        for (int reg = 0; reg < 4; ++reg) {
            const int r = row0 + wr * 64 + mi * 16 + g * 4 + reg;
            if (r < M) {
                const float sc = s[r];
                #pragma unroll
                for (int ni = 0; ni < 4; ++ni) {
                    C[(size_t)r * Ncols + col0 + wc * 64 + ni * 16 + lm] = f2h(acc[mi][ni][reg] * sc);
                }
            }
        }
    }
}

// ---------------- fused CSR-gather (fp16 payload) + dual-attention ----------------
template <int F, int VEC, bool LEAKY01, bool FUSE_FC, bool OUT_SPLIT>
__global__ __launch_bounds__(256)
void gather_attn_kernel(const u16* __restrict__ pre,
                        const int* __restrict__ rowptr,
                        const int* __restrict__ csr,
                        const float* __restrict__ sin_,
                        const float* __restrict__ bb0, const float* __restrict__ bb1,
                        const float* __restrict__ bb2,
                        const float* __restrict__ a,
                        const float* __restrict__ fcw,
                        const float* __restrict__ fcb,
                        float* __restrict__ out,
                        u16* __restrict__ outh, u16* __restrict__ outl,
                        float* __restrict__ logits,
                        int Nn, int E)
{
    const int wave = blockIdx.x * 4 + (threadIdx.x >> 6);
    const int lane = threadIdx.x & 63;
    if (wave >= Nn) return;
    const int n = wave;
    const size_t NF = (size_t)Nn * F;
    const int fo = lane * VEC;

    float ht[3][VEC];
    float mean[VEC];
    #pragma unroll
    for (int v = 0; v < VEC; ++v) mean[v] = 0.f;

    const float* bptr[3] = {bb0, bb1, bb2};
    #pragma unroll
    for (int t = 0; t < 3; ++t) {
        const int* rp = rowptr + (size_t)t * (Nn + 1);
        const int beg = rp[n];
        const int end = rp[n + 1];
        const int* lst = csr + (size_t)t * E;
        const u16* P = pre + t * NF;

        float a0v[VEC], a1v[VEC], a2v[VEC], a3v[VEC];
        #pragma unroll
        for (int v = 0; v < VEC; ++v) { a0v[v] = 0.f; a1v[v] = 0.f; a2v[v] = 0.f; a3v[v] = 0.f; }

        for (int j = beg; j < end; j += 64) {
            const int cnt = min(64, end - j);
            int myIdx = (lane < cnt) ? lst[j + lane] : 0;
            int k = 0;
            for (; k + 4 <= cnt; k += 4) {
                const int s0 = __shfl(myIdx, k + 0);
                const int s1 = __shfl(myIdx, k + 1);
                const int s2 = __shfl(myIdx, k + 2);
                const int s3 = __shfl(myIdx, k + 3);
                if constexpr (VEC == 4) {
                    u16x4 r0 = *reinterpret_cast<const u16x4*>(P + (size_t)s0 * F + fo);
                    u16x4 r1 = *reinterpret_cast<const u16x4*>(P + (size_t)s1 * F + fo);
                    u16x4 r2 = *reinterpret_cast<const u16x4*>(P + (size_t)s2 * F + fo);
                    u16x4 r3 = *reinterpret_cast<const u16x4*>(P + (size_t)s3 * F + fo);
                    #pragma unroll
                    for (int v = 0; v < 4; ++v) a0v[v] += h2f(r0[v]);
                    #pragma unroll
                    for (int v = 0; v < 4; ++v) a1v[v] += h2f(r1[v]);
                    #pragma unroll
                    for (int v = 0; v < 4; ++v) a2v[v] += h2f(r2[v]);
                    #pragma unroll
                    for (int v = 0; v < 4; ++v) a3v[v] += h2f(r3[v]);
                } else {
                    u16x2 r0 = *reinterpret_cast<const u16x2*>(P + (size_t)s0 * F + fo);
                    u16x2 r1 = *reinterpret_cast<const u16x2*>(P + (size_t)s1 * F + fo);
                    u16x2 r2 = *reinterpret_cast<const u16x2*>(P + (size_t)s2 * F + fo);
                    u16x2 r3 = *reinterpret_cast<const u16x2*>(P + (size_t)s3 * F + fo);
                    a0v[0] += h2f(r0[0]); a0v[1] += h2f(r0[1]);
                    a1v[0] += h2f(r1[0]); a1v[1] += h2f(r1[1]);
                    a2v[0] += h2f(r2[0]); a2v[1] += h2f(r2[1]);
                    a3v[0] += h2f(r3[0]); a3v[1] += h2f(r3[1]);
                }
            }
            for (; k < cnt; ++k) {
                const int sI = __shfl(myIdx, k);
                const u16* rowp = P + (size_t)sI * F + fo;
                if constexpr (VEC == 4) {
                    u16x4 r4 = *reinterpret_cast<const u16x4*>(rowp);
                    #pragma unroll
                    for (int v = 0; v < 4; ++v) a0v[v] += h2f(r4[v]);
                } else {
                    u16x2 r2 = *reinterpret_cast<const u16x2*>(rowp);
                    a0v[0] += h2f(r2[0]); a0v[1] += h2f(r2[1]);
                }
            }
        }

        const float si = sin_[t * Nn + n];
        const float* bp = bptr[t] + fo;
        #pragma unroll
        for (int v = 0; v < VEC; ++v) {
            const float sum = (a0v[v] + a1v[v]) + (a2v[v] + a3v[v]);
            const float xv = fmaf(sum, si, bp[v]);
            ht[t][v] = xv;
            mean[v] += xv;
        }
    }
    #pragma unroll
    for (int v = 0; v < VEC; ++v) mean[v] *= (1.0f / 3.0f);

    float p0 = 0.f, p1 = 0.f, p2 = 0.f, p3 = 0.f;
    #pragma unroll
    for (int v = 0; v < VEC; ++v) {
        const float aA = a[fo + v];
        const float aB = a[F + fo + v];
        p0 = fmaf(ht[0][v], aA, p0);
        p1 = fmaf(ht[1][v], aA, p1);
        p2 = fmaf(ht[2][v], aA, p2);
        p3 = fmaf(mean[v], aB, p3);
    }
    #pragma unroll
    for (int off = 1; off < 64; off <<= 1) {
        p0 += __shfl_xor(p0, off);
        p1 += __shfl_xor(p1, off);
        p2 += __shfl_xor(p2, off);
        p3 += __shfl_xor(p3, off);
    }
    float sc0 = p0 + p3, sc1 = p1 + p3, sc2 = p2 + p3;
    sc0 = sc0 > 0.f ? sc0 : 0.2f * sc0;
    sc1 = sc1 > 0.f ? sc1 : 0.2f * sc1;
    sc2 = sc2 > 0.f ? sc2 : 0.2f * sc2;
    const float m = fmaxf(sc0, fmaxf(sc1, sc2));
    const float e0 = __expf(sc0 - m);
    const float e1 = __expf(sc1 - m);
    const float e2 = __expf(sc2 - m);
    const float inv = 1.0f / (e0 + e1 + e2);
    const float at0 = e0 * inv, at1 = e1 * inv, at2 = e2 * inv;

    float o[VEC];
    #pragma unroll
    for (int v = 0; v < VEC; ++v) {
        float ov = at0 * ht[0][v] + at1 * ht[1][v] + at2 * ht[2][v];
        if constexpr (LEAKY01) ov = ov > 0.f ? ov : 0.01f * ov;
        o[v] = ov;
    }

    if constexpr (OUT_SPLIT) {
        u16 oh[VEC], ol[VEC];
        #pragma unroll
        for (int v = 0; v < VEC; ++v) {
            u16 hi = f2bf_rne(o[v]);
            oh[v] = hi;
            ol[v] = f2bf_rne(o[v] - bf2f(hi));
        }
        if constexpr (VEC == 4) {
            *(u16x4*)(outh + (size_t)n * F + fo) = *(u16x4*)oh;
            *(u16x4*)(outl + (size_t)n * F + fo) = *(u16x4*)ol;
        } else {
            *(u16x2*)(outh + (size_t)n * F + fo) = *(u16x2*)oh;
            *(u16x2*)(outl + (size_t)n * F + fo) = *(u16x2*)ol;
        }
    } else {
        float* op = out + (size_t)n * F + fo;
        #pragma unroll
        for (int v = 0; v < VEC; ++v) op[v] = o[v];
    }

    if constexpr (FUSE_FC) {
        float accc[10];
        #pragma unroll
        for (int c = 0; c < 10; ++c) {
            float s = 0.f;
            #pragma unroll
            for (int v = 0; v < VEC; ++v)
                s = fmaf(o[v], fcw[(fo + v) * 10 + c], s);
            accc[c] = s;
        }
        #pragma unroll
        for (int off = 1; off < 64; off <<= 1) {
            #pragma unroll
            for (int c = 0; c < 10; ++c) accc[c] += __shfl_xor(accc[c], off);
        }
        if (lane == 0) {
            #pragma unroll
            for (int c = 0; c < 10; ++c)
                logits[(size_t)n * 10 + c] = accc[c] + fcb[c];
        }
    }
}

extern "C" void kernel_launch(void* const* d_in, const int* in_sizes, int n_in,
                              void* d_out, int out_size, void* d_ws, size_t ws_size,
                              hipStream_t stream)
{
    const float* x = (const float*)d_in[0];
    const int* src[3] = {(const int*)d_in[1], (const int*)d_in[3], (const int*)d_in[5]};
    const int* dst[3] = {(const int*)d_in[2], (const int*)d_in[4], (const int*)d_in[6]};
    const float* W0[3] = {(const float*)d_in[7],  (const float*)d_in[11], (const float*)d_in[15]};
    const float* b0[3] = {(const float*)d_in[8],  (const float*)d_in[12], (const float*)d_in[16]};
    const float* W1[3] = {(const float*)d_in[9],  (const float*)d_in[13], (const float*)d_in[17]};
    const float* b1[3] = {(const float*)d_in[10], (const float*)d_in[14], (const float*)d_in[18]};
    const float* a0  = (const float*)d_in[19];
    const float* a1  = (const float*)d_in[20];
    const float* fcw = (const float*)d_in[21];
    const float* fcb = (const float*)d_in[22];

    const int Nn = in_sizes[0] / 300;  // 20000
    const int E  = in_sizes[1];        // 320000
    const int K1p = 320, F1 = 256;
    const int K2p = 256, F2 = 128;
    const int Mpad = ((Nn + 127) / 128) * 128;  // 20096

    // ---- workspace layout ----
    char* wsb = (char*)d_ws;
    size_t off = 0;
    auto take = [&](size_t bytes) { char* p = wsb + off; off = (off + bytes + 15) & ~(size_t)15; return p; };
    // persistent
    int*   deg    = (int*)take(6 * (size_t)Nn * sizeof(int));
    float* scales = (float*)take(6 * (size_t)Nn * sizeof(float));
    int*   rowptr = (int*)take(3 * ((size_t)Nn + 1) * sizeof(int));
    int*   csr    = (int*)take(3 * (size_t)E * sizeof(int));
    u16*   wt1h   = (u16*)take(3 * (size_t)F1 * K1p * sizeof(u16));
    u16*   wt1l   = (u16*)take(3 * (size_t)F1 * K1p * sizeof(u16));
    u16*   wt2h   = (u16*)take(3 * (size_t)F2 * K2p * sizeof(u16));
    u16*   wt2l   = (u16*)take(3 * (size_t)F2 * K2p * sizeof(u16));
    // union region: CSR-build temps (hist+offu) vs GEMM-phase buffers
    const size_t histB = 6 * (size_t)GG * Nn * sizeof(u16);
    const size_t offuB = 3 * (size_t)GG * Nn * sizeof(u32);
    const size_t gemmB = (3 * (size_t)Nn * 256 + 2 * (size_t)Mpad * K1p + 2 * (size_t)Mpad * K2p) * sizeof(u16);
    char* region = (char*)take(histB + offuB > gemmB ? histB + offuB : gemmB);
    u16* hist = (u16*)region;
    u32* offu = (u32*)(region + ((histB + 15) & ~(size_t)15));
    u16* buf1 = (u16*)region;
    u16* xh   = buf1 + 3 * (size_t)Nn * 256;
    u16* xl   = xh + (size_t)Mpad * K1p;
    u16* h1h  = xl + (size_t)Mpad * K1p;
    u16* h1l  = h1h + (size_t)Mpad * K2p;

    float* outH   = (float*)d_out;
    float* logits = outH + (size_t)Nn * 128;

    // ---- CSR build (no global atomics) ----
    {
        dim3 g(GG, 2, 3);
        hist_kernel<<<g, 256, 0, stream>>>(src[0], dst[0], src[1], dst[1],
                                           src[2], dst[2], hist, E, Nn);
    }
    sumdeg_scales_kernel<<<(6 * Nn + 255) / 256, 256, 0, stream>>>(hist, deg, scales, Nn);
    scan_rowptr_kernel<<<3, 1024, 0, stream>>>(deg, rowptr, Nn);
    offsets_kernel<<<(3 * Nn + 255) / 256, 256, 0, stream>>>(hist, rowptr, offu, Nn);
    {
        dim3 g(GG, 1, 3);
        fill_csr_kernel<<<g, 256, 0, stream>>>(src[0], dst[0], src[1], dst[1],
                                               src[2], dst[2], offu, csr, E, Nn);
    }

    // ---- all conversions in one launch (after CSR build: buffers alias hist/offu) ----
    {
        const int n1 = 3 * F1 * K1p;
        const int n2 = 3 * F2 * K2p;
        const int n3 = Mpad * K1p;
        const int total = n1 + n2 + n3;
        convert_all_kernel<<<(total + 255) / 256, 256, 0, stream>>>(
            x, W0[0], W0[1], W0[2], W1[0], W1[1], W1[2],
            wt1h, wt1l, wt2h, wt2l, xh, xl, Nn, n1, n2, n3);
    }

    // ---- layer 1 ----
    {
        dim3 g(F1 / 128, Mpad / 128, 3);
        mfma_gemm_kernel<10><<<g, 256, 0, stream>>>(
            xh, xl,
            wt1h + 0 * (size_t)F1 * K1p, wt1l + 0 * (size_t)F1 * K1p,
            wt1h + 1 * (size_t)F1 * K1p, wt1l + 1 * (size_t)F1 * K1p,
            wt1h + 2 * (size_t)F1 * K1p, wt1l + 2 * (size_t)F1 * K1p,
            scales, buf1, Nn, F1);
    }
    gather_attn_kernel<256, 4, true, false, true><<<(Nn + 3) / 4, 256, 0, stream>>>(
        buf1, rowptr, csr, scales + 3 * (size_t)Nn,
        b0[0], b0[1], b0[2], a0, nullptr, nullptr,
        nullptr, h1h, h1l, nullptr, Nn, E);

    // ---- layer 2 ----
    {
        dim3 g(F2 / 128, Mpad / 128, 3);
        mfma_gemm_kernel<8><<<g, 256, 0, stream>>>(
            h1h, h1l,
            wt2h + 0 * (size_t)F2 * K2p, wt2l + 0 * (size_t)F2 * K2p,
            wt2h + 1 * (size_t)F2 * K2p, wt2l + 1 * (size_t)F2 * K2p,
            wt2h + 2 * (size_t)F2 * K2p, wt2l + 2 * (size_t)F2 * K2p,
            scales, buf1, Nn, F2);
    }
    gather_attn_kernel<128, 2, false, true, false><<<(Nn + 3) / 4, 256, 0, stream>>>(
        buf1, rowptr, csr, scales + 3 * (size_t)Nn,
        b1[0], b1[1], b1[2], a1, fcw, fcb,
        outH, nullptr, nullptr, logits, Nn, E);
}